// Round 5
// baseline (145.948 us; speedup 1.0000x reference)
//
#include <hip/hip_runtime.h>
#include <hip/hip_bf16.h>

#define N_CHR 23
#define N_EMB 512   // K (codebook)
#define E_DIM 128   // E
#define B_SZ  4
#define L_SEQ 2048
#define LOG2E 1.4426950408889634f
#define LOG2_LOG2E 0.5287663729448977f   // log2(log2(e)):  exp(r)=2^(r*log2e)=2^(2^(t+C)) for r=2^t

typedef __attribute__((ext_vector_type(8))) short short8;
typedef __attribute__((ext_vector_type(4))) float floatx4;
typedef __attribute__((ext_vector_type(2))) float f32x2;

#if __has_builtin(__builtin_amdgcn_exp2f)
#define EXP2(x) __builtin_amdgcn_exp2f(x)
#else
#define EXP2(x) __expf((x) * 0.6931471805599453f)
#endif

#if __has_builtin(__builtin_amdgcn_rcpf)
#define RCP(x) __builtin_amdgcn_rcpf(x)
#else
#define RCP(x) (1.0f / (x))
#endif

__device__ __forceinline__ float bf2f(unsigned short u) {
    return __uint_as_float(((unsigned)u) << 16);
}
__device__ __forceinline__ unsigned short f2bf(float f) {
    unsigned u = __float_as_uint(f);
    unsigned r = u + 0x7FFFu + ((u >> 16) & 1u);
    return (unsigned short)(r >> 16);
}

// ---------------- Pre-pass: emb fp32 -> bf16, MFMA-B-fragment-linear ----------
// embw[((c*16 + ch)*8 + nt)*64 + lane] (uint4) = B[k=ch*32+quad*8+j][n=nt*16+(lane&15)]
// j=0..7 packed bf16 low-half-first. 23*16*8*64 uint4 = 2.9 MB.
__global__ __launch_bounds__(256) void emb_pack_kernel(
    const float* __restrict__ emb, uint4* __restrict__ embw)
{
    const int idx  = blockIdx.x * 256 + threadIdx.x;
    const int lane = idx & 63;
    const int nt   = (idx >> 6) & 7;
    const int ch   = (idx >> 9) & 15;
    const int c    = idx >> 13;
    if (c >= N_CHR) return;
    const int quad = lane >> 4;
    const int n    = nt * 16 + (lane & 15);
    const float* src = emb + (size_t)(c * N_EMB + ch * 32 + quad * 8) * E_DIM + n;
    unsigned v[8];
#pragma unroll
    for (int j = 0; j < 8; ++j) v[j] = (unsigned)f2bf(src[j * E_DIM]);
    uint4 w;
    w.x = v[0] | (v[1] << 16);
    w.y = v[2] | (v[3] << 16);
    w.z = v[4] | (v[5] << 16);
    w.w = v[6] | (v[7] << 16);
    embw[idx] = w;
}

// ---------------- Main kernel --------------------------------------------------
// 64 rows x 128 cols per block; K-chunks of 32, prefetch-distance-1 async B
// staging; A = p built in-register with packed f32 math; softmax denominator
// via a 9th MFMA against a ones-B fragment (lands in C/D row layout directly).
__global__ __launch_bounds__(256, 7) void rbf_emb_kernel(
    const float* __restrict__ pos,   // [B, C, L]  f32
    const uint4* __restrict__ embw,  // pre-packed bf16 frag-linear
    const float* __restrict__ ctr,   // [C, K]     f32
    const float* __restrict__ lvar,  // [C, K]     f32
    float* __restrict__ out)         // [B, C*L, E] f32
{
    __shared__ float2 cs_s[N_EMB];   // {center, -log2e/(2*var)}  4KB
    __shared__ uint4 Bs[2][512];     // double-buffered 32x128 bf16 chunk, 16KB

    const int tid  = threadIdx.x;
    const int lane = tid & 63;
    const int wave = tid >> 6;
    const int quad = lane >> 4;
    const int m    = lane & 15;

    const int bc   = blockIdx.x >> 5;   // 0..91  (b*23 + c)
    const int mt   = blockIdx.x & 31;   // 0..31
    const int c    = bc % N_CHR;
    const int row0 = mt * 64;

    const uint4* gbase = embw + (size_t)c * (16 * 8 * 64);

    // kick off chunk-0 staging before anything else (no cs_s dependency)
    {
        const uint4* g = gbase + wave * 128 + lane;
        __builtin_amdgcn_global_load_lds(
            (const __attribute__((address_space(1))) void*)(g),
            (__attribute__((address_space(3))) void*)(&Bs[0][wave * 128]), 16, 0, 0);
        __builtin_amdgcn_global_load_lds(
            (const __attribute__((address_space(1))) void*)(g + 64),
            (__attribute__((address_space(3))) void*)(&Bs[0][wave * 128 + 64]), 16, 0, 0);
    }

    for (int k = tid; k < N_EMB; k += 256) {
        cs_s[k] = make_float2(ctr[c * N_EMB + k],
                              -0.5f * LOG2E * __expf(-lvar[c * N_EMB + k]));
    }

    const float posf = pos[bc * L_SEQ + row0 + wave * 16 + m];

    floatx4 acc[8];
#pragma unroll
    for (int i = 0; i < 8; ++i) acc[i] = (floatx4){0.f, 0.f, 0.f, 0.f};
    floatx4 accd = (floatx4){0.f, 0.f, 0.f, 0.f};

    short8 bones;
#pragma unroll
    for (int j = 0; j < 8; ++j) bones[j] = (short)0x3F80;   // bf16 1.0

    // A fragment for chunk ch: A[m=lane&15][k=quad*8+j], p = 2^(2^(d^2*s + C))
    auto computeA = [&](int ch) -> short8 {
        const float4* cs4 = ((const float4*)cs_s) + ch * 16 + quad * 4;
        unsigned pk[4];
#pragma unroll
        for (int jj = 0; jj < 4; ++jj) {
            const float4 q = cs4[jj];                 // {c0,s0,c1,s1}
            f32x2 cc = {q.x, q.z};
            f32x2 ss = {q.y, q.w};
            f32x2 d  = (f32x2){posf, posf} - cc;      // v_pk_add
            f32x2 t  = d * d;                         // v_pk_mul
            t = t * ss + (f32x2){LOG2_LOG2E, LOG2_LOG2E};  // v_pk_fma
            const float p0 = EXP2(EXP2(t.x));
            const float p1 = EXP2(EXP2(t.y));
            union { __hip_bfloat162 h; unsigned u; } cv;
            cv.h = __float22bfloat162_rn(make_float2(p0, p1));  // v_cvt_pk_bf16_f32 (RNE)
            pk[jj] = cv.u;
        }
        const int4 v = make_int4((int)pk[0], (int)pk[1], (int)pk[2], (int)pk[3]);
        return __builtin_bit_cast(short8, v);
    };

    __syncthreads();                // cs_s ready (also drains chunk-0 staging)
    short8 aNext = computeA(0);

    for (int ch = 0; ch < 16; ++ch) {
        __syncthreads();            // Bs[ch&1] staged; prior buffer reads drained

        if (ch < 15) {              // prefetch chunk ch+1 (lands during MFMA + next A)
            const uint4* g = gbase + (ch + 1) * 512 + wave * 128 + lane;
            uint4* bw = Bs[(ch + 1) & 1];
            __builtin_amdgcn_global_load_lds(
                (const __attribute__((address_space(1))) void*)(g),
                (__attribute__((address_space(3))) void*)(bw + wave * 128), 16, 0, 0);
            __builtin_amdgcn_global_load_lds(
                (const __attribute__((address_space(1))) void*)(g + 64),
                (__attribute__((address_space(3))) void*)(bw + wave * 128 + 64), 16, 0, 0);
        }

        const short8 a = aNext;
        const uint4* br = Bs[ch & 1];

        accd = __builtin_amdgcn_mfma_f32_16x16x32_bf16(a, bones, accd, 0, 0, 0);
#pragma unroll
        for (int nt = 0; nt < 8; ++nt) {
            short8 bfrag = *(const short8*)&br[(nt << 6) + lane];  // ds_read_b128
            acc[nt] = __builtin_amdgcn_mfma_f32_16x16x32_bf16(a, bfrag, acc[nt], 0, 0, 0);
        }

        if (ch < 15) aNext = computeA(ch + 1);   // exp chain overlaps prefetch
    }

    // --- epilogue: C/D layout col = lane&15, row = quad*4 + reg ---
    // accd[reg] = denom of row quad*4+reg (all 16 cols identical).
    float* outp = out + (size_t)(bc * L_SEQ + row0 + wave * 16) * E_DIM;
#pragma unroll
    for (int reg = 0; reg < 4; ++reg) {
        const float inv = RCP(accd[reg]);
        float* o = outp + (quad * 4 + reg) * E_DIM + m;
#pragma unroll
        for (int nt = 0; nt < 8; ++nt) {
            o[nt * 16] = acc[nt][reg] * inv;
        }
    }
}

// ---------------- Fallback (round-3 kernel, used if ws too small) -------------
__global__ __launch_bounds__(256, 4) void rbf_emb_kernel_slow(
    const float* __restrict__ pos, const float* __restrict__ emb,
    const float* __restrict__ ctr, const float* __restrict__ lvar,
    float* __restrict__ out)
{
    __shared__ float centers_s[N_EMB];
    __shared__ float scale_s[N_EMB];
    __shared__ uint4 Bs[2][512];
    __shared__ float inv_s[64];

    const int tid  = threadIdx.x;
    const int lane = tid & 63;
    const int wave = tid >> 6;
    const int quad = lane >> 4;
    const int m    = lane & 15;
    const int bc   = blockIdx.x >> 5;
    const int mt   = blockIdx.x & 31;
    const int c    = bc % N_CHR;
    const int row0 = mt * 64;

    for (int k = tid; k < N_EMB; k += 256) {
        centers_s[k] = ctr[c * N_EMB + k];
        scale_s[k]   = -0.5f * __expf(-lvar[c * N_EMB + k]);
    }
    const float posf = pos[bc * L_SEQ + row0 + wave * 16 + m];
    floatx4 acc[8];
#pragma unroll
    for (int i = 0; i < 8; ++i) acc[i] = (floatx4){0.f, 0.f, 0.f, 0.f};
    float denom = 0.f;
    __syncthreads();

    const int n_st = tid & 127;
    const int qd0  = tid >> 7;
    const float* embc = emb + (size_t)c * (N_EMB * E_DIM);

    for (int ch = 0; ch < 16; ++ch) {
        const int kc = ch * 32;
        uint4* bw = Bs[ch & 1];
#pragma unroll
        for (int qq = 0; qq < 2; ++qq) {
            const int qd = qd0 + qq * 2;
            const float* src = embc + (kc + qd * 8) * E_DIM + n_st;
            unsigned v[8];
#pragma unroll
            for (int j = 0; j < 8; ++j) v[j] = (unsigned)f2bf(src[j * E_DIM]);
            uint4 w;
            w.x = v[0] | (v[1] << 16);
            w.y = v[2] | (v[3] << 16);
            w.z = v[4] | (v[5] << 16);
            w.w = v[6] | (v[7] << 16);
            bw[((n_st >> 4) << 6) + (qd << 4) + (n_st & 15)] = w;
        }
        short8 afrag;
#pragma unroll
        for (int j = 0; j < 8; ++j) {
            const int   k   = kc + quad * 8 + j;
            const float d   = posf - centers_s[k];
            const float rbf = __expf(d * d * scale_s[k]);
            const float p   = __expf(rbf);
            const unsigned short pb = f2bf(p);
            afrag[j] = (short)pb;
            denom += bf2f(pb);
        }
        __syncthreads();
        const uint4* br = bw;
#pragma unroll
        for (int nt = 0; nt < 8; ++nt) {
            short8 bfrag = *(const short8*)&br[(nt << 6) + lane];
            acc[nt] = __builtin_amdgcn_mfma_f32_16x16x32_bf16(afrag, bfrag, acc[nt], 0, 0, 0);
        }
    }
    denom += __shfl_xor(denom, 16);
    denom += __shfl_xor(denom, 32);
    if (lane < 16) inv_s[wave * 16 + m] = 1.0f / denom;
    __syncthreads();
    float* outp = out + (size_t)(bc * L_SEQ + row0 + wave * 16) * E_DIM;
#pragma unroll
    for (int reg = 0; reg < 4; ++reg) {
        const int   r   = quad * 4 + reg;
        const float inv = inv_s[wave * 16 + r];
        float* o = outp + r * E_DIM + m;
#pragma unroll
        for (int nt = 0; nt < 8; ++nt) o[nt * 16] = acc[nt][reg] * inv;
    }
}

extern "C" void kernel_launch(void* const* d_in, const int* in_sizes, int n_in,
                              void* d_out, int out_size, void* d_ws, size_t ws_size,
                              hipStream_t stream) {
    // d_in: [0]=chromosome(int32, unused), [1]=position(f32), [2]=embeddings(f32),
    //       [3]=centers(f32), [4]=log_variances(f32)
    const float* pos  = (const float*)d_in[1];
    const float* emb  = (const float*)d_in[2];
    const float* ctr  = (const float*)d_in[3];
    const float* lvar = (const float*)d_in[4];
    float* out = (float*)d_out;

    const int    blocks    = (B_SZ * N_CHR) * (L_SEQ / 64);       // 2944
    const size_t ws_needed = (size_t)N_CHR * 16 * 8 * 64 * 16;    // 2.9 MB

    if (ws_size >= ws_needed) {
        uint4* embw = (uint4*)d_ws;
        emb_pack_kernel<<<(N_CHR * 16 * 8 * 64) / 256, 256, 0, stream>>>(emb, embw);
        rbf_emb_kernel<<<blocks, 256, 0, stream>>>(pos, embw, ctr, lvar, out);
    } else {
        rbf_emb_kernel_slow<<<blocks, 256, 0, stream>>>(pos, emb, ctr, lvar, out);
    }
}

// Round 6
// 143.763 us; speedup vs baseline: 1.0152x; 1.0152x over previous
//
#include <hip/hip_runtime.h>
#include <hip/hip_bf16.h>

#define N_CHR 23
#define N_EMB 512   // K (codebook)
#define E_DIM 128   // E
#define B_SZ  4
#define L_SEQ 2048
#define LOG2E 1.4426950408889634f
#define LOG2_LOG2E 0.5287663729448977f   // exp(r) = 2^(2^(t + C)) where r = 2^t

typedef __attribute__((ext_vector_type(8))) short short8;
typedef __attribute__((ext_vector_type(4))) float floatx4;
typedef __attribute__((ext_vector_type(2))) float f32x2;

#if __has_builtin(__builtin_amdgcn_exp2f)
#define EXP2(x) __builtin_amdgcn_exp2f(x)
#else
#define EXP2(x) __expf((x) * 0.6931471805599453f)
#endif

#if __has_builtin(__builtin_amdgcn_rcpf)
#define RCP(x) __builtin_amdgcn_rcpf(x)
#else
#define RCP(x) (1.0f / (x))
#endif

__device__ __forceinline__ float bf2f(unsigned short u) {
    return __uint_as_float(((unsigned)u) << 16);
}
__device__ __forceinline__ unsigned short f2bf(float f) {
    unsigned u = __float_as_uint(f);
    unsigned r = u + 0x7FFFu + ((u >> 16) & 1u);
    return (unsigned short)(r >> 16);
}

// ---------------- Pre-pass: emb fp32 -> bf16, MFMA-B-fragment-linear ----------
// embw[((c*16 + ch)*8 + nt)*64 + lane] (uint4) = B[k=ch*32+quad*8+j][n=nt*16+(lane&15)]
// j=0..7 packed bf16 low-half-first. 23*16*8*64 uint4 = 2.9 MB.
__global__ __launch_bounds__(256) void emb_pack_kernel(
    const float* __restrict__ emb, uint4* __restrict__ embw)
{
    const int idx  = blockIdx.x * 256 + threadIdx.x;
    const int lane = idx & 63;
    const int nt   = (idx >> 6) & 7;
    const int ch   = (idx >> 9) & 15;
    const int c    = idx >> 13;
    if (c >= N_CHR) return;
    const int quad = lane >> 4;
    const int n    = nt * 16 + (lane & 15);
    const float* src = emb + (size_t)(c * N_EMB + ch * 32 + quad * 8) * E_DIM + n;
    unsigned v[8];
#pragma unroll
    for (int j = 0; j < 8; ++j) v[j] = (unsigned)f2bf(src[j * E_DIM]);
    uint4 w;
    w.x = v[0] | (v[1] << 16);
    w.y = v[2] | (v[3] << 16);
    w.z = v[4] | (v[5] << 16);
    w.w = v[6] | (v[7] << 16);
    embw[idx] = w;
}

// ---------------- Main kernel --------------------------------------------------
// Block: 4 waves, 128 rows x 128 cols. Each wave owns TWO 16-row M-tiles so the
// 8 B-fragment ds_read_b128 per chunk feed 16 MFMAs (halves LDS read traffic —
// round-5 lesson: kernel is LDS-BW bound, not VALU bound). Prefetch-distance-1
// async B staging; denominator via ones-B MFMA per tile.
__global__ __launch_bounds__(256, 4) void rbf_emb_kernel(
    const float* __restrict__ pos,   // [B, C, L]  f32
    const uint4* __restrict__ embw,  // pre-packed bf16 frag-linear
    const float* __restrict__ ctr,   // [C, K]     f32
    const float* __restrict__ lvar,  // [C, K]     f32
    float* __restrict__ out)         // [B, C*L, E] f32
{
    __shared__ float2 cs_s[N_EMB];   // {center, -log2e/(2*var)}  4KB
    __shared__ uint4 Bs[2][512];     // double-buffered 32x128 bf16 chunk, 16KB

    const int tid  = threadIdx.x;
    const int lane = tid & 63;
    const int wave = tid >> 6;
    const int quad = lane >> 4;
    const int m    = lane & 15;

    const int bc   = blockIdx.x >> 4;   // 0..91  (b*23 + c)
    const int mt   = blockIdx.x & 15;   // 0..15
    const int c    = bc % N_CHR;
    const int row0 = mt * 128;

    const uint4* gbase = embw + (size_t)c * (16 * 8 * 64);

    // kick off chunk-0 staging before anything else (no cs_s dependency)
    {
        const uint4* g = gbase + wave * 128 + lane;
        __builtin_amdgcn_global_load_lds(
            (const __attribute__((address_space(1))) void*)(g),
            (__attribute__((address_space(3))) void*)(&Bs[0][wave * 128]), 16, 0, 0);
        __builtin_amdgcn_global_load_lds(
            (const __attribute__((address_space(1))) void*)(g + 64),
            (__attribute__((address_space(3))) void*)(&Bs[0][wave * 128 + 64]), 16, 0, 0);
    }

    for (int k = tid; k < N_EMB; k += 256) {
        cs_s[k] = make_float2(ctr[c * N_EMB + k],
                              -0.5f * LOG2E * __expf(-lvar[c * N_EMB + k]));
    }

    // wave covers rows [row0 + wave*32, +32): tile0 at +0, tile1 at +16
    const float posf0 = pos[bc * L_SEQ + row0 + wave * 32 + m];
    const float posf1 = pos[bc * L_SEQ + row0 + wave * 32 + 16 + m];

    floatx4 acc0[8], acc1[8];
#pragma unroll
    for (int i = 0; i < 8; ++i) {
        acc0[i] = (floatx4){0.f, 0.f, 0.f, 0.f};
        acc1[i] = (floatx4){0.f, 0.f, 0.f, 0.f};
    }
    floatx4 accd0 = (floatx4){0.f, 0.f, 0.f, 0.f};
    floatx4 accd1 = (floatx4){0.f, 0.f, 0.f, 0.f};

    short8 bones;
#pragma unroll
    for (int j = 0; j < 8; ++j) bones[j] = (short)0x3F80;   // bf16 1.0

    // A fragments for chunk ch, both tiles: A[m=lane&15][k=quad*8+j]
    short8 aN0, aN1;
    auto computeA2 = [&](int ch) {
        const float4* cs4 = ((const float4*)cs_s) + ch * 16 + quad * 4;
        unsigned pk0[4], pk1[4];
#pragma unroll
        for (int jj = 0; jj < 4; ++jj) {
            const float4 q = cs4[jj];                 // {c0,s0,c1,s1}
            const f32x2 cc = {q.x, q.z};
            const f32x2 ss = {q.y, q.w};
            const f32x2 C2 = {LOG2_LOG2E, LOG2_LOG2E};
            f32x2 d0 = (f32x2){posf0, posf0} - cc;
            f32x2 d1 = (f32x2){posf1, posf1} - cc;
            f32x2 t0 = d0 * d0 * ss + C2;
            f32x2 t1 = d1 * d1 * ss + C2;
            const float p00 = EXP2(EXP2(t0.x));
            const float p01 = EXP2(EXP2(t0.y));
            const float p10 = EXP2(EXP2(t1.x));
            const float p11 = EXP2(EXP2(t1.y));
            union { __hip_bfloat162 h; unsigned u; } cv0, cv1;
            cv0.h = __float22bfloat162_rn(make_float2(p00, p01));
            cv1.h = __float22bfloat162_rn(make_float2(p10, p11));
            pk0[jj] = cv0.u;
            pk1[jj] = cv1.u;
        }
        aN0 = __builtin_bit_cast(short8, make_int4((int)pk0[0], (int)pk0[1], (int)pk0[2], (int)pk0[3]));
        aN1 = __builtin_bit_cast(short8, make_int4((int)pk1[0], (int)pk1[1], (int)pk1[2], (int)pk1[3]));
    };

    __syncthreads();                // cs_s ready (also drains chunk-0 staging)
    computeA2(0);

    for (int ch = 0; ch < 16; ++ch) {
        __syncthreads();            // Bs[ch&1] staged; prior buffer reads drained

        if (ch < 15) {              // prefetch chunk ch+1
            const uint4* g = gbase + (ch + 1) * 512 + wave * 128 + lane;
            uint4* bw = Bs[(ch + 1) & 1];
            __builtin_amdgcn_global_load_lds(
                (const __attribute__((address_space(1))) void*)(g),
                (__attribute__((address_space(3))) void*)(bw + wave * 128), 16, 0, 0);
            __builtin_amdgcn_global_load_lds(
                (const __attribute__((address_space(1))) void*)(g + 64),
                (__attribute__((address_space(3))) void*)(bw + wave * 128 + 64), 16, 0, 0);
        }

        const short8 a0 = aN0, a1 = aN1;
        const uint4* br = Bs[ch & 1];

        accd0 = __builtin_amdgcn_mfma_f32_16x16x32_bf16(a0, bones, accd0, 0, 0, 0);
        accd1 = __builtin_amdgcn_mfma_f32_16x16x32_bf16(a1, bones, accd1, 0, 0, 0);
#pragma unroll
        for (int nt = 0; nt < 8; ++nt) {
            short8 bfrag = *(const short8*)&br[(nt << 6) + lane];  // ds_read_b128
            acc0[nt] = __builtin_amdgcn_mfma_f32_16x16x32_bf16(a0, bfrag, acc0[nt], 0, 0, 0);
            acc1[nt] = __builtin_amdgcn_mfma_f32_16x16x32_bf16(a1, bfrag, acc1[nt], 0, 0, 0);
        }

        if (ch < 15) computeA2(ch + 1);   // exp chain overlaps prefetch + MFMA
    }

    // --- epilogue: C/D layout col = lane&15, row = quad*4 + reg ---
    float* outp0 = out + (size_t)(bc * L_SEQ + row0 + wave * 32) * E_DIM;
    float* outp1 = outp0 + 16 * E_DIM;
#pragma unroll
    for (int reg = 0; reg < 4; ++reg) {
        const float inv0 = RCP(accd0[reg]);
        const float inv1 = RCP(accd1[reg]);
        float* o0 = outp0 + (quad * 4 + reg) * E_DIM + m;
        float* o1 = outp1 + (quad * 4 + reg) * E_DIM + m;
#pragma unroll
        for (int nt = 0; nt < 8; ++nt) {
            o0[nt * 16] = acc0[nt][reg] * inv0;
            o1[nt * 16] = acc1[nt][reg] * inv1;
        }
    }
}

// ---------------- Fallback (round-3 kernel, used if ws too small) -------------
__global__ __launch_bounds__(256, 4) void rbf_emb_kernel_slow(
    const float* __restrict__ pos, const float* __restrict__ emb,
    const float* __restrict__ ctr, const float* __restrict__ lvar,
    float* __restrict__ out)
{
    __shared__ float centers_s[N_EMB];
    __shared__ float scale_s[N_EMB];
    __shared__ uint4 Bs[2][512];
    __shared__ float inv_s[64];

    const int tid  = threadIdx.x;
    const int lane = tid & 63;
    const int wave = tid >> 6;
    const int quad = lane >> 4;
    const int m    = lane & 15;
    const int bc   = blockIdx.x >> 5;
    const int mt   = blockIdx.x & 31;
    const int c    = bc % N_CHR;
    const int row0 = mt * 64;

    for (int k = tid; k < N_EMB; k += 256) {
        centers_s[k] = ctr[c * N_EMB + k];
        scale_s[k]   = -0.5f * __expf(-lvar[c * N_EMB + k]);
    }
    const float posf = pos[bc * L_SEQ + row0 + wave * 16 + m];
    floatx4 acc[8];
#pragma unroll
    for (int i = 0; i < 8; ++i) acc[i] = (floatx4){0.f, 0.f, 0.f, 0.f};
    float denom = 0.f;
    __syncthreads();

    const int n_st = tid & 127;
    const int qd0  = tid >> 7;
    const float* embc = emb + (size_t)c * (N_EMB * E_DIM);

    for (int ch = 0; ch < 16; ++ch) {
        const int kc = ch * 32;
        uint4* bw = Bs[ch & 1];
#pragma unroll
        for (int qq = 0; qq < 2; ++qq) {
            const int qd = qd0 + qq * 2;
            const float* src = embc + (kc + qd * 8) * E_DIM + n_st;
            unsigned v[8];
#pragma unroll
            for (int j = 0; j < 8; ++j) v[j] = (unsigned)f2bf(src[j * E_DIM]);
            uint4 w;
            w.x = v[0] | (v[1] << 16);
            w.y = v[2] | (v[3] << 16);
            w.z = v[4] | (v[5] << 16);
            w.w = v[6] | (v[7] << 16);
            bw[((n_st >> 4) << 6) + (qd << 4) + (n_st & 15)] = w;
        }
        short8 afrag;
#pragma unroll
        for (int j = 0; j < 8; ++j) {
            const int   k   = kc + quad * 8 + j;
            const float d   = posf - centers_s[k];
            const float rbf = __expf(d * d * scale_s[k]);
            const float p   = __expf(rbf);
            const unsigned short pb = f2bf(p);
            afrag[j] = (short)pb;
            denom += bf2f(pb);
        }
        __syncthreads();
        const uint4* br = bw;
#pragma unroll
        for (int nt = 0; nt < 8; ++nt) {
            short8 bfrag = *(const short8*)&br[(nt << 6) + lane];
            acc[nt] = __builtin_amdgcn_mfma_f32_16x16x32_bf16(afrag, bfrag, acc[nt], 0, 0, 0);
        }
    }
    denom += __shfl_xor(denom, 16);
    denom += __shfl_xor(denom, 32);
    if (lane < 16) inv_s[wave * 16 + m] = 1.0f / denom;
    __syncthreads();
    float* outp = out + (size_t)(bc * L_SEQ + row0 + wave * 16) * E_DIM;
#pragma unroll
    for (int reg = 0; reg < 4; ++reg) {
        const int   r   = quad * 4 + reg;
        const float inv = inv_s[wave * 16 + r];
        float* o = outp + r * E_DIM + m;
#pragma unroll
        for (int nt = 0; nt < 8; ++nt) o[nt * 16] = acc[nt][reg] * inv;
    }
}

extern "C" void kernel_launch(void* const* d_in, const int* in_sizes, int n_in,
                              void* d_out, int out_size, void* d_ws, size_t ws_size,
                              hipStream_t stream) {
    // d_in: [0]=chromosome(int32, unused), [1]=position(f32), [2]=embeddings(f32),
    //       [3]=centers(f32), [4]=log_variances(f32)
    const float* pos  = (const float*)d_in[1];
    const float* emb  = (const float*)d_in[2];
    const float* ctr  = (const float*)d_in[3];
    const float* lvar = (const float*)d_in[4];
    float* out = (float*)d_out;

    const size_t ws_needed = (size_t)N_CHR * 16 * 8 * 64 * 16;    // 2.9 MB

    if (ws_size >= ws_needed) {
        uint4* embw = (uint4*)d_ws;
        emb_pack_kernel<<<(N_CHR * 16 * 8 * 64) / 256, 256, 0, stream>>>(emb, embw);
        const int blocks = (B_SZ * N_CHR) * (L_SEQ / 128);        // 1472
        rbf_emb_kernel<<<blocks, 256, 0, stream>>>(pos, embw, ctr, lvar, out);
    } else {
        const int blocks = (B_SZ * N_CHR) * (L_SEQ / 64);         // 2944
        rbf_emb_kernel_slow<<<blocks, 256, 0, stream>>>(pos, emb, ctr, lvar, out);
    }
}